// Round 10
// baseline (299.701 us; speedup 1.0000x reference)
//
#include <hip/hip_runtime.h>
#include <hip/hip_cooperative_groups.h>
#include <math.h>

namespace cg = cooperative_groups;

#define N_NODES 100000
#define N_EDGES 3200000
#define EPS_F 1e-6f
#define PAIRS   (N_EDGES / 2)           // 1,600,000

// ---- prep geometry: 256 blocks x 1024 thr, 160 KB bf16 v-table in LDS ----
#define TBL_N   80000                   // bf16 nodes in LDS (160,000 B); rest spill to L2
#define GNB     256
#define GSTRIDE (GNB * 1024)            // 262,144 threads
#define NVARW   (GNB * 16)              // per-wave varsum partials (4096)

// ---- scatter: R8-proven geometry (grid 256, 50 KB bins, PART store flush) ----
// R0-R9 closure: scatter time is invariant ~37-43 us across scan volume (102 vs
// 205 MB), waves (16/32), iterations (3/7) -> bound by the 6.4M LDS-atomic
// lane-ops (25,000/CU, ~3.5 cyc each). Irreducible; keep best-measured config.
#define SLICE_N 12500                   // 8*12500 = 100000
#define NSLICE  8
#define NCHUNK  32
#define C_PAIRS (PAIRS / NCHUNK)        // 50000 pairs per chunk (800 KB)
#define SBATCH  8

#define NKCLB   391                     // fallback kcl blocks
#define NPACKB  196

// ws layout (4-byte words) — ~38.7 MB
#define CNT_WORD  32
#define PK_OFF    64
#define PART_OFF  (PK_OFF + 2 * N_EDGES)          // 6,400,064
#define VARP_OFF  (PART_OFF + NCHUNK * N_NODES)   // 9,600,064
#define KCLP_OFF  (VARP_OFF + 4 * NVARW)          // 9,616,448  (256 or 391 entries)
#define VBF_OFF   (KCLP_OFF + 512)                // 9,616,960
#define WS_FLOATS (VBF_OFF + N_NODES / 2 + 64)

__device__ __forceinline__ float wave_reduce(float v) {
    #pragma unroll
    for (int off = 32; off > 0; off >>= 1) v += __shfl_down(v, off, 64);
    return v;
}

__device__ __forceinline__ void fadd_agent(float* p, float v) {
    unsafeAtomicAdd(p, v);
}

// bf16 pack/unpack (RNE)
__device__ __forceinline__ unsigned short f2bf(float f) {
    unsigned u = __float_as_uint(f);
    unsigned r = ((u >> 16) & 1u) + 0x7FFFu;
    return (unsigned short)((u + r) >> 16);
}
__device__ __forceinline__ float bf2f(unsigned short h) {
    return __uint_as_float(((unsigned)h) << 16);
}

// ==================== FUSED cooperative kernel (single dispatch) ====================
// 256 blocks x 1024 thr, 160 KB LDS -> exactly 1 block/CU, co-resident by
// construction; grid.sync() provides the cross-XCD-coherent barrier (G16).
// Phases: pack -> prep -> scatter -> kcl -> final, replacing 4 dispatches
// (~9 us/boundary) with 4 grid syncs.
__global__ __launch_bounds__(1024, 4) void fused_kernel(
    const float*  __restrict__ nf,
    const void*   __restrict__ eidx,
    const float*  __restrict__ logits,
    const float2* __restrict__ params,
    float*        __restrict__ ws,
    float*        __restrict__ out)
{
    cg::grid_group grid = cg::this_grid();

    __shared__ union {
        unsigned table[TBL_N / 2];   // 160,000 B  (phase 1)
        float    bins[SLICE_N];      //  50,000 B  (phase 2)
        float    sc[16];             // phase 3 block-reduce scratch
        float    red2[16][5];        // phase 4 scratch
    } u;

    const int t  = threadIdx.x;
    const int b  = blockIdx.x;
    const int gt = b * 1024 + t;

    // ---------------- phase 0: pack v -> bf16 table ----------------
    if (gt < N_NODES / 2) {
        const float4 a = ((const float4*)nf)[2 * gt];       // node 2t   (v = .x)
        const float4 c = ((const float4*)nf)[2 * gt + 1];   // node 2t+1 (v = .x)
        ((unsigned*)(ws + VBF_OFF))[gt] = (unsigned)f2bf(a.x) | ((unsigned)f2bf(c.x) << 16);
    }
    grid.sync();

    // ---------------- phase 1: prep (LDS v-table gather, ILP-4) ----------------
    {
        const unsigned* vsrc = (const unsigned*)(ws + VBF_OFF);
        for (int j = t; j < TBL_N / 2; j += 1024) u.table[j] = vsrc[j];

        const int* i32 = (const int*)eidx;
        int any = 0;
        #pragma unroll
        for (int k = 1; k < 32; k += 2) any |= i32[k];
        const bool is32 = (any != 0);

        __syncthreads();
        const unsigned short* vl = (const unsigned short*)u.table;
        const unsigned short* vg = (const unsigned short*)(ws + VBF_OFF);

        int4* pk = (int4*)(ws + PK_OFF);
        float s0 = 0.f, s1 = 0.f, q0 = 0.f, q1 = 0.f;

        #define VGET(id) bf2f(((unsigned)(id) < TBL_N) ? vl[id] : vg[id])

        for (int p = gt; p < PAIRS; p += 4 * GSTRIDE) {
            int pi[4];
            #pragma unroll
            for (int uu = 0; uu < 4; ++uu) {
                const int pp = p + uu * GSTRIDE;
                pi[uu] = (pp < PAIRS) ? pp : p;   // clamp: loads stay unconditional
            }

            int2 sp[4], dp[4];
            if (is32) {
                #pragma unroll
                for (int uu = 0; uu < 4; ++uu) {
                    sp[uu] = ((const int2*)i32)[pi[uu]];
                    dp[uu] = ((const int2*)(i32 + N_EDGES))[pi[uu]];
                }
            } else {
                #pragma unroll
                for (int uu = 0; uu < 4; ++uu) {
                    const int4 a = ((const int4*)i32)[pi[uu]];
                    const int4 c = ((const int4*)(i32 + 2 * N_EDGES))[pi[uu]];
                    sp[uu] = make_int2(a.x, a.z);
                    dp[uu] = make_int2(c.x, c.z);
                }
            }

            float4 ppr[4];
            float2 lgr[4];
            #pragma unroll
            for (int uu = 0; uu < 4; ++uu) {
                ppr[uu] = ((const float4*)params)[pi[uu]];
                lgr[uu] = ((const float2*)logits)[pi[uu]];
            }

            float vs0[4], vd0[4], vs1[4], vd1[4];
            #pragma unroll
            for (int uu = 0; uu < 4; ++uu) {
                vs0[uu] = VGET(sp[uu].x);  vd0[uu] = VGET(dp[uu].x);
                vs1[uu] = VGET(sp[uu].y);  vd1[uu] = VGET(dp[uu].y);
            }

            #pragma unroll
            for (int uu = 0; uu < 4; ++uu) {
                const int pp = p + uu * GSTRIDE;
                const float w0 = (1.0f / (1.0f + __expf(-lgr[uu].x))) / (ppr[uu].x + ppr[uu].y + EPS_F);
                const float w1 = (1.0f / (1.0f + __expf(-lgr[uu].y))) / (ppr[uu].z + ppr[uu].w + EPS_F);
                const float c0 = fabsf(vs0[uu] - vd0[uu]) * w0;
                const float c1 = fabsf(vs1[uu] - vd1[uu]) * w1;

                int4 o;
                o.x = (int)((unsigned)sp[uu].x | ((unsigned)dp[uu].x << 17));
                o.y = (int)((((unsigned)dp[uu].x) >> 15) | ((unsigned)f2bf(c0) << 2));
                o.z = (int)((unsigned)sp[uu].y | ((unsigned)dp[uu].y << 17));
                o.w = (int)((((unsigned)dp[uu].y) >> 15) | ((unsigned)f2bf(c1) << 2));

                if (pp < PAIRS) {
                    pk[pp] = o;
                    s0 += ppr[uu].x + ppr[uu].z;
                    s1 += ppr[uu].y + ppr[uu].w;
                    q0 += ppr[uu].x * ppr[uu].x + ppr[uu].z * ppr[uu].z;
                    q1 += ppr[uu].y * ppr[uu].y + ppr[uu].w * ppr[uu].w;
                }
            }
        }
        #undef VGET

        s0 = wave_reduce(s0); s1 = wave_reduce(s1);
        q0 = wave_reduce(q0); q1 = wave_reduce(q1);
        if ((t & 63) == 0) {
            float4 o; o.x = s0; o.y = s1; o.z = q0; o.w = q1;
            ((float4*)(ws + VARP_OFF))[b * 16 + (t >> 6)] = o;
        }
    }
    grid.sync();

    // ---------------- phase 2: LDS-binned scatter (R8 geometry) ----------------
    {
        const int c  = b & (NCHUNK - 1);
        const int s  = b >> 5;
        const unsigned lo = (unsigned)(s * SLICE_N);

        for (int j = t; j < SLICE_N; j += 1024) u.bins[j] = 0.f;
        __syncthreads();

        const int4* pk = (const int4*)(ws + PK_OFF);
        const int p0 = c * C_PAIRS;
        const int p1 = p0 + C_PAIRS;

        for (int base = p0 + t; base < p1; base += 1024 * SBATCH) {
            int4 q[SBATCH];
            #pragma unroll
            for (int k = 0; k < SBATCH; ++k) {
                int p = base + k * 1024;
                p = (p < p1) ? p : (p1 - 1);   // clamp: loads stay unconditional
                q[k] = pk[p];
            }
            #pragma unroll
            for (int k = 0; k < SBATCH; ++k) {
                const int p = base + k * 1024;
                if (p < p1) {
                    const unsigned lo0 = (unsigned)q[k].x, hi0 = (unsigned)q[k].y;
                    const unsigned lo1 = (unsigned)q[k].z, hi1 = (unsigned)q[k].w;
                    const unsigned s0 = (lo0 & 0x1FFFFu) - lo;
                    const unsigned d0 = ((lo0 >> 17) | ((hi0 & 3u) << 15)) - lo;
                    const unsigned s1 = (lo1 & 0x1FFFFu) - lo;
                    const unsigned d1 = ((lo1 >> 17) | ((hi1 & 3u) << 15)) - lo;
                    const float c0 = bf2f((unsigned short)((hi0 >> 2) & 0xFFFFu));
                    const float c1 = bf2f((unsigned short)((hi1 >> 2) & 0xFFFFu));
                    if (d0 < SLICE_N) atomicAdd(&u.bins[d0],  c0);
                    if (s0 < SLICE_N) atomicAdd(&u.bins[s0], -c0);
                    if (d1 < SLICE_N) atomicAdd(&u.bins[d1],  c1);
                    if (s1 < SLICE_N) atomicAdd(&u.bins[s1], -c1);
                }
            }
        }
        __syncthreads();

        float4* pt4 = (float4*)(ws + PART_OFF + (size_t)c * N_NODES + lo);
        for (int j = t; j < SLICE_N / 4; j += 1024)
            pt4[j] = ((const float4*)u.bins)[j];
    }
    grid.sync();

    // ---------------- phase 3: per-node merge + square, block partial ----------------
    {
        float acc = 0.f;
        if (gt < N_NODES) {
            const float* p = ws + PART_OFF + gt;
            float s = 0.f;
            #pragma unroll 8
            for (int c = 0; c < NCHUNK; ++c) s += p[(size_t)c * N_NODES];
            acc = s * s;
        }
        acc = wave_reduce(acc);
        __syncthreads();                       // union reuse guard
        if ((t & 63) == 0) u.sc[t >> 6] = acc;
        __syncthreads();
        if (t == 0) {
            float s = 0.f;
            #pragma unroll
            for (int w = 0; w < 16; ++w) s += u.sc[w];
            ws[KCLP_OFF + b] = s;
        }
    }
    grid.sync();

    // ---------------- phase 4: final reduction (block 0) ----------------
    if (b == 0) {
        float s0 = 0.f, s1 = 0.f, q0 = 0.f, q1 = 0.f, k = 0.f;

        const float4* vp = (const float4*)(ws + VARP_OFF);
        for (int j = t; j < NVARW; j += 1024) {
            const float4 v = vp[j];
            s0 += v.x; s1 += v.y; q0 += v.z; q1 += v.w;
        }
        for (int j = t; j < GNB; j += 1024) k += ws[KCLP_OFF + j];

        s0 = wave_reduce(s0); s1 = wave_reduce(s1);
        q0 = wave_reduce(q0); q1 = wave_reduce(q1);
        k  = wave_reduce(k);

        __syncthreads();                       // union reuse guard
        const int wid = t >> 6;
        if ((t & 63) == 0) {
            u.red2[wid][0] = s0; u.red2[wid][1] = s1; u.red2[wid][2] = q0;
            u.red2[wid][3] = q1; u.red2[wid][4] = k;
        }
        __syncthreads();
        if (t == 0) {
            float a0 = 0.f, a1 = 0.f, a2 = 0.f, a3 = 0.f, a4 = 0.f;
            #pragma unroll
            for (int w = 0; w < 16; ++w) {
                a0 += u.red2[w][0]; a1 += u.red2[w][1]; a2 += u.red2[w][2];
                a3 += u.red2[w][3]; a4 += u.red2[w][4];
            }
            const float n    = (float)N_EDGES;
            const float var0 = (a2 - a0 * a0 / n) / (n - 1.0f);
            const float var1 = (a3 - a1 * a1 / n) / (n - 1.0f);
            out[0] = a4 / (float)N_NODES + 0.5f * (var0 + var1);
        }
    }
}

// ==================== R8 multi-kernel path (non-cooperative fallback) ====================

__global__ __launch_bounds__(256) void pack_kernel(
    const float* __restrict__ nf, float* __restrict__ ws)
{
    const int t = blockIdx.x * 256 + threadIdx.x;
    if (t == 0) ((unsigned*)ws)[CNT_WORD] = 0;
    if (t < N_NODES / 2) {
        const float4 a = ((const float4*)nf)[2 * t];
        const float4 b = ((const float4*)nf)[2 * t + 1];
        ((unsigned*)(ws + VBF_OFF))[t] = (unsigned)f2bf(a.x) | ((unsigned)f2bf(b.x) << 16);
    }
}

__global__ __launch_bounds__(1024, 4) void prep_kernel(
    const void*   __restrict__ eidx,
    const float*  __restrict__ logits,
    const float2* __restrict__ params,
    float*        __restrict__ ws)
{
    __shared__ unsigned vlds[TBL_N / 2];

    const unsigned* vsrc = (const unsigned*)(ws + VBF_OFF);
    for (int j = threadIdx.x; j < TBL_N / 2; j += 1024) vlds[j] = vsrc[j];

    const int* i32 = (const int*)eidx;
    int any = 0;
    #pragma unroll
    for (int k = 1; k < 32; k += 2) any |= i32[k];
    const bool is32 = (any != 0);

    __syncthreads();
    const unsigned short* vl = (const unsigned short*)vlds;
    const unsigned short* vg = (const unsigned short*)(ws + VBF_OFF);

    const int gtid = blockIdx.x * 1024 + threadIdx.x;
    int4* pk = (int4*)(ws + PK_OFF);
    float s0 = 0.f, s1 = 0.f, q0 = 0.f, q1 = 0.f;

    #define VGET(id) bf2f(((unsigned)(id) < TBL_N) ? vl[id] : vg[id])
    for (int p = gtid; p < PAIRS; p += 4 * GSTRIDE) {
        int pi[4];
        #pragma unroll
        for (int u = 0; u < 4; ++u) {
            const int pp = p + u * GSTRIDE;
            pi[u] = (pp < PAIRS) ? pp : p;
        }
        int2 sp[4], dp[4];
        if (is32) {
            #pragma unroll
            for (int u = 0; u < 4; ++u) {
                sp[u] = ((const int2*)i32)[pi[u]];
                dp[u] = ((const int2*)(i32 + N_EDGES))[pi[u]];
            }
        } else {
            #pragma unroll
            for (int u = 0; u < 4; ++u) {
                const int4 a = ((const int4*)i32)[pi[u]];
                const int4 b = ((const int4*)(i32 + 2 * N_EDGES))[pi[u]];
                sp[u] = make_int2(a.x, a.z);
                dp[u] = make_int2(b.x, b.z);
            }
        }
        float4 ppr[4];
        float2 lgr[4];
        #pragma unroll
        for (int u = 0; u < 4; ++u) {
            ppr[u] = ((const float4*)params)[pi[u]];
            lgr[u] = ((const float2*)logits)[pi[u]];
        }
        float vs0[4], vd0[4], vs1[4], vd1[4];
        #pragma unroll
        for (int u = 0; u < 4; ++u) {
            vs0[u] = VGET(sp[u].x);  vd0[u] = VGET(dp[u].x);
            vs1[u] = VGET(sp[u].y);  vd1[u] = VGET(dp[u].y);
        }
        #pragma unroll
        for (int u = 0; u < 4; ++u) {
            const int pp = p + u * GSTRIDE;
            const float w0 = (1.0f / (1.0f + __expf(-lgr[u].x))) / (ppr[u].x + ppr[u].y + EPS_F);
            const float w1 = (1.0f / (1.0f + __expf(-lgr[u].y))) / (ppr[u].z + ppr[u].w + EPS_F);
            const float c0 = fabsf(vs0[u] - vd0[u]) * w0;
            const float c1 = fabsf(vs1[u] - vd1[u]) * w1;
            int4 o;
            o.x = (int)((unsigned)sp[u].x | ((unsigned)dp[u].x << 17));
            o.y = (int)((((unsigned)dp[u].x) >> 15) | ((unsigned)f2bf(c0) << 2));
            o.z = (int)((unsigned)sp[u].y | ((unsigned)dp[u].y << 17));
            o.w = (int)((((unsigned)dp[u].y) >> 15) | ((unsigned)f2bf(c1) << 2));
            if (pp < PAIRS) {
                pk[pp] = o;
                s0 += ppr[u].x + ppr[u].z;
                s1 += ppr[u].y + ppr[u].w;
                q0 += ppr[u].x * ppr[u].x + ppr[u].z * ppr[u].z;
                q1 += ppr[u].y * ppr[u].y + ppr[u].w * ppr[u].w;
            }
        }
    }
    #undef VGET

    s0 = wave_reduce(s0); s1 = wave_reduce(s1);
    q0 = wave_reduce(q0); q1 = wave_reduce(q1);
    if ((threadIdx.x & 63) == 0) {
        float4 o; o.x = s0; o.y = s1; o.z = q0; o.w = q1;
        ((float4*)(ws + VARP_OFF))[blockIdx.x * 16 + (threadIdx.x >> 6)] = o;
    }
}

__global__ __launch_bounds__(1024) void scatter_kernel(float* __restrict__ ws)
{
    __shared__ float bins[SLICE_N];

    const int c  = blockIdx.x & (NCHUNK - 1);
    const int s  = blockIdx.x >> 5;
    const unsigned lo = (unsigned)(s * SLICE_N);

    for (int j = threadIdx.x; j < SLICE_N; j += 1024) bins[j] = 0.f;
    __syncthreads();

    const int4* pk = (const int4*)(ws + PK_OFF);
    const int p0 = c * C_PAIRS;
    const int p1 = p0 + C_PAIRS;

    for (int base = p0 + (int)threadIdx.x; base < p1; base += 1024 * SBATCH) {
        int4 q[SBATCH];
        #pragma unroll
        for (int k = 0; k < SBATCH; ++k) {
            int p = base + k * 1024;
            p = (p < p1) ? p : (p1 - 1);
            q[k] = pk[p];
        }
        #pragma unroll
        for (int k = 0; k < SBATCH; ++k) {
            const int p = base + k * 1024;
            if (p < p1) {
                const unsigned lo0 = (unsigned)q[k].x, hi0 = (unsigned)q[k].y;
                const unsigned lo1 = (unsigned)q[k].z, hi1 = (unsigned)q[k].w;
                const unsigned s0 = (lo0 & 0x1FFFFu) - lo;
                const unsigned d0 = ((lo0 >> 17) | ((hi0 & 3u) << 15)) - lo;
                const unsigned s1 = (lo1 & 0x1FFFFu) - lo;
                const unsigned d1 = ((lo1 >> 17) | ((hi1 & 3u) << 15)) - lo;
                const float c0 = bf2f((unsigned short)((hi0 >> 2) & 0xFFFFu));
                const float c1 = bf2f((unsigned short)((hi1 >> 2) & 0xFFFFu));
                if (d0 < SLICE_N) atomicAdd(&bins[d0],  c0);
                if (s0 < SLICE_N) atomicAdd(&bins[s0], -c0);
                if (d1 < SLICE_N) atomicAdd(&bins[d1],  c1);
                if (s1 < SLICE_N) atomicAdd(&bins[s1], -c1);
            }
        }
    }
    __syncthreads();

    float4* pt4 = (float4*)(ws + PART_OFF + (size_t)c * N_NODES + lo);
    for (int j = threadIdx.x; j < SLICE_N / 4; j += 1024)
        pt4[j] = ((const float4*)bins)[j];
}

__global__ __launch_bounds__(256) void kclfinal_kernel(float* __restrict__ ws,
                                                       float* __restrict__ out)
{
    __shared__ float red[4];
    __shared__ unsigned last;

    const int i = blockIdx.x * blockDim.x + threadIdx.x;
    float acc = 0.f;
    if (i < N_NODES) {
        const float* p = ws + PART_OFF + i;
        float s = 0.f;
        #pragma unroll 8
        for (int c = 0; c < NCHUNK; ++c) s += p[(size_t)c * N_NODES];
        acc = s * s;
    }
    acc = wave_reduce(acc);
    if ((threadIdx.x & 63) == 0) red[threadIdx.x >> 6] = acc;
    __syncthreads();
    if (threadIdx.x == 0) {
        ws[KCLP_OFF + blockIdx.x] = red[0] + red[1] + red[2] + red[3];
        __threadfence();
        const unsigned old = atomicAdd((unsigned*)ws + CNT_WORD, 1u);
        last = (old == NKCLB - 1) ? 1u : 0u;
    }
    __syncthreads();
    if (!last) return;

    __shared__ float red2[4][5];
    float s0 = 0.f, s1 = 0.f, q0 = 0.f, q1 = 0.f, k = 0.f;

    const float4* vp = (const float4*)(ws + VARP_OFF);
    for (int j = threadIdx.x; j < NVARW; j += 256) {
        const float4 v = vp[j];
        s0 += v.x; s1 += v.y; q0 += v.z; q1 += v.w;
    }
    for (int j = threadIdx.x; j < NKCLB; j += 256)
        k += unsafeAtomicAdd(ws + KCLP_OFF + j, 0.0f);

    s0 = wave_reduce(s0); s1 = wave_reduce(s1);
    q0 = wave_reduce(q0); q1 = wave_reduce(q1);
    k  = wave_reduce(k);

    const int wid = threadIdx.x >> 6;
    if ((threadIdx.x & 63) == 0) {
        red2[wid][0] = s0; red2[wid][1] = s1; red2[wid][2] = q0;
        red2[wid][3] = q1; red2[wid][4] = k;
    }
    __syncthreads();
    if (threadIdx.x == 0) {
        float a0 = 0.f, a1 = 0.f, a2 = 0.f, a3 = 0.f, a4 = 0.f;
        #pragma unroll
        for (int w = 0; w < 4; ++w) {
            a0 += red2[w][0]; a1 += red2[w][1]; a2 += red2[w][2];
            a3 += red2[w][3]; a4 += red2[w][4];
        }
        const float n    = (float)N_EDGES;
        const float var0 = (a2 - a0 * a0 / n) / (n - 1.0f);
        const float var1 = (a3 - a1 * a1 / n) / (n - 1.0f);
        out[0] = a4 / (float)N_NODES + 0.5f * (var0 + var1);
    }
}

// ---------------- fallback (ws too small): agent-atomic scatter ----------------
#define FB_NODE_OFF 64
__global__ __launch_bounds__(256) void edge_kernel_fb(
    const float*  __restrict__ nf,
    const void*   __restrict__ eidx,
    const float*  __restrict__ logits,
    const float2* __restrict__ params,
    float*        __restrict__ ws)
{
    const int*       i32 = (const int*)eidx;
    const long long* i64 = (const long long*)eidx;
    int any = 0;
    #pragma unroll
    for (int k = 1; k < 32; k += 2) any |= i32[k];
    const bool is32 = (any != 0);

    float* node_sum = ws + FB_NODE_OFF;
    float* acc      = ws + 1;

    float s0 = 0.f, s1 = 0.f, q0 = 0.f, q1 = 0.f;
    const int tid    = blockIdx.x * blockDim.x + threadIdx.x;
    const int stride = gridDim.x * blockDim.x;
    for (int i = tid; i < N_EDGES; i += stride) {
        int src, dst;
        if (is32) { src = i32[i]; dst = i32[N_EDGES + i]; }
        else      { src = (int)i64[i]; dst = (int)i64[N_EDGES + i]; }
        const float2 ep = params[i];
        const float  p  = 1.0f / (1.0f + __expf(-logits[i]));
        const float cur = fabsf(nf[src * 4] - nf[dst * 4]) / (ep.x + ep.y + EPS_F) * p;
        fadd_agent(node_sum + dst,  cur);
        fadd_agent(node_sum + src, -cur);
        s0 += ep.x; s1 += ep.y; q0 += ep.x * ep.x; q1 += ep.y * ep.y;
    }
    s0 = wave_reduce(s0); s1 = wave_reduce(s1);
    q0 = wave_reduce(q0); q1 = wave_reduce(q1);
    if ((threadIdx.x & 63) == 0) {
        fadd_agent(acc + 0, s0); fadd_agent(acc + 1, s1);
        fadd_agent(acc + 2, q0); fadd_agent(acc + 3, q1);
    }
}

__global__ __launch_bounds__(256) void kcl_kernel_fb(float* __restrict__ ws)
{
    const float* node_sum = ws + FB_NODE_OFF;
    float acc = 0.f;
    const int tid    = blockIdx.x * blockDim.x + threadIdx.x;
    const int stride = gridDim.x * blockDim.x;
    for (int i = tid; i < N_NODES; i += stride) {
        const float v = node_sum[i];
        acc += v * v;
    }
    acc = wave_reduce(acc);
    if ((threadIdx.x & 63) == 0) fadd_agent(ws + 5, acc);
}

__global__ void final_kernel_fb(const float* __restrict__ ws, float* __restrict__ out)
{
    const float s0 = ws[1], s1 = ws[2], q0 = ws[3], q1 = ws[4], k = ws[5];
    const float n  = (float)N_EDGES;
    const float var0 = (q0 - s0 * s0 / n) / (n - 1.0f);
    const float var1 = (q1 - s1 * s1 / n) / (n - 1.0f);
    out[0] = k / (float)N_NODES + 0.5f * (var0 + var1);
}

extern "C" void kernel_launch(void* const* d_in, const int* in_sizes, int n_in,
                              void* d_out, int out_size, void* d_ws, size_t ws_size,
                              hipStream_t stream) {
    const float*  nf     = (const float*)d_in[0];
    const void*   eidx   = d_in[1];
    const float*  logits = (const float*)d_in[2];
    const float2* params = (const float2*)d_in[3];
    float* ws  = (float*)d_ws;
    float* out = (float*)d_out;

    const size_t need = (size_t)WS_FLOATS * sizeof(float);   // ~38.7 MB

    if (ws_size >= need) {
        void* kargs[6];
        kargs[0] = (void*)&nf;     kargs[1] = (void*)&eidx;
        kargs[2] = (void*)&logits; kargs[3] = (void*)&params;
        kargs[4] = (void*)&ws;     kargs[5] = (void*)&out;
        const hipError_t e = hipLaunchCooperativeKernel(
            (const void*)fused_kernel, dim3(GNB), dim3(1024), kargs, 0, stream);
        if (e != hipSuccess) {
            (void)hipGetLastError();   // clear; fall back to proven 4-kernel path
            pack_kernel<<<NPACKB, 256, 0, stream>>>(nf, ws);
            prep_kernel<<<GNB, 1024, 0, stream>>>(eidx, logits, params, ws);
            scatter_kernel<<<NCHUNK * NSLICE, 1024, 0, stream>>>(ws);
            kclfinal_kernel<<<NKCLB, 256, 0, stream>>>(ws, out);
        }
    } else {
        hipMemsetAsync(d_ws, 0, 256 + (size_t)N_NODES * sizeof(float), stream);
        edge_kernel_fb<<<2048, 256, 0, stream>>>(nf, eidx, logits, params, ws);
        kcl_kernel_fb<<<200, 256, 0, stream>>>(ws);
        final_kernel_fb<<<1, 1, 0, stream>>>(ws, out);
    }
}

// Round 11
// 175.452 us; speedup vs baseline: 1.7082x; 1.7082x over previous
//
#include <hip/hip_runtime.h>
#include <math.h>

#define N_NODES 100000
#define N_EDGES 3200000
#define EPS_F 1e-6f
#define PAIRS   (N_EDGES / 2)           // 1,600,000

// ---- prep geometry: 256 blocks x 1024 thr, 160 KB bf16 v-table in LDS ----
// Table filled DIRECTLY from nf (L2/L3-resident 1.6 MB): pack dispatch deleted.
#define TBL_N   80000                   // bf16 nodes in LDS (160,000 B); rest read nf fp32
#define GNB     256
#define GSTRIDE (GNB * 1024)            // 262,144 threads
#define NVARW   (GNB * 16)              // per-wave varsum partials (4096)

// ---- scatter: R8-proven geometry (grid 256, 50 KB bins, PART store flush) ----
// R0-R9 closure: scatter is bound by 6.4M LDS-atomic lane-ops (~3.5 cyc each,
// 25,000/CU -> ~37 us) — invariant across scan volume, waves, iteration depth.
#define SLICE_N 12500                   // 8*12500 = 100000
#define NSLICE  8
#define NCHUNK  32
#define C_PAIRS (PAIRS / NCHUNK)        // 50000 pairs per chunk (800 KB)
#define SBATCH  8

#define NKCLB   98                      // ceil(100000/1024): fewer blocks, less tail

// ws layout (4-byte words) — ~38.5 MB
//   CNT_WORD : done-counter (reset by prep, gt==0)
//   PK_OFF   : u64 pack[N_EDGES]  lo = src | dst<<17 ; hi = (dst>>15) | cur<<2
//   PART_OFF : partials[NCHUNK=32][N_NODES]  (12.8 MB)
//   VARP_OFF : per-WAVE float4 {s0,s1,q0,q1}[NVARW]
//   KCLP_OFF : per-block kcl partial [NKCLB]
#define CNT_WORD  32
#define PK_OFF    64
#define PART_OFF  (PK_OFF + 2 * N_EDGES)          // 6,400,064
#define VARP_OFF  (PART_OFF + NCHUNK * N_NODES)   // 9,600,064
#define KCLP_OFF  (VARP_OFF + 4 * NVARW)          // 9,616,448
#define WS_FLOATS (KCLP_OFF + NKCLB + 64)

__device__ __forceinline__ float wave_reduce(float v) {
    #pragma unroll
    for (int off = 32; off > 0; off >>= 1) v += __shfl_down(v, off, 64);
    return v;
}

__device__ __forceinline__ void fadd_agent(float* p, float v) {
    unsafeAtomicAdd(p, v);   // fallback / final-reduce read path
}

// bf16 pack/unpack (RNE)
__device__ __forceinline__ unsigned short f2bf(float f) {
    unsigned u = __float_as_uint(f);
    unsigned r = ((u >> 16) & 1u) + 0x7FFFu;
    return (unsigned short)((u + r) >> 16);
}
__device__ __forceinline__ float bf2f(unsigned short h) {
    return __uint_as_float(((unsigned)h) << 16);
}

// ---------------- pass 1: prep = LDS v-table (from nf) + pack ids+cur + varsum ----------------
// Each block fills its own 80000-entry bf16 table from the L2/L3-resident v
// column (stride-16B reads; 2B LDS writes are 2-way bank aliasing = free).
// Spill ids (>= TBL_N, ~20%) read nf fp32 directly (L2-hit). ILP-4 pairs.
__global__ __launch_bounds__(1024, 4) void prep_kernel(
    const float*  __restrict__ nf,
    const void*   __restrict__ eidx,
    const float*  __restrict__ logits,
    const float2* __restrict__ params,
    float*        __restrict__ ws)
{
    __shared__ unsigned short vl[TBL_N];   // 160,000 B

    const int gtid = blockIdx.x * 1024 + threadIdx.x;
    if (gtid == 0) ((unsigned*)ws)[CNT_WORD] = 0;   // done-counter for kclfinal

    for (int j = threadIdx.x; j < TBL_N; j += 1024) vl[j] = f2bf(nf[j * 4]);

    const int* i32 = (const int*)eidx;
    // int64 values < 2^31 have zero hi-words at every odd int32 slot;
    // int32 has random node ids there (16 zeros ~ impossible).
    int any = 0;
    #pragma unroll
    for (int k = 1; k < 32; k += 2) any |= i32[k];
    const bool is32 = (any != 0);

    __syncthreads();

    int4* pk = (int4*)(ws + PK_OFF);
    float s0 = 0.f, s1 = 0.f, q0 = 0.f, q1 = 0.f;

    #define VGET(id) (((unsigned)(id) < TBL_N) ? bf2f(vl[id]) : nf[(id) * 4])

    for (int p = gtid; p < PAIRS; p += 4 * GSTRIDE) {
        int pi[4];
        #pragma unroll
        for (int u = 0; u < 4; ++u) {
            const int pp = p + u * GSTRIDE;
            pi[u] = (pp < PAIRS) ? pp : p;   // clamp: loads stay unconditional
        }

        int2 sp[4], dp[4];
        if (is32) {
            #pragma unroll
            for (int u = 0; u < 4; ++u) {
                sp[u] = ((const int2*)i32)[pi[u]];
                dp[u] = ((const int2*)(i32 + N_EDGES))[pi[u]];
            }
        } else {
            #pragma unroll
            for (int u = 0; u < 4; ++u) {
                const int4 a = ((const int4*)i32)[pi[u]];
                const int4 b = ((const int4*)(i32 + 2 * N_EDGES))[pi[u]];
                sp[u] = make_int2(a.x, a.z);
                dp[u] = make_int2(b.x, b.z);
            }
        }

        float4 ppr[4];
        float2 lgr[4];
        #pragma unroll
        for (int u = 0; u < 4; ++u) {
            ppr[u] = ((const float4*)params)[pi[u]];
            lgr[u] = ((const float2*)logits)[pi[u]];
        }

        float vs0[4], vd0[4], vs1[4], vd1[4];
        #pragma unroll
        for (int u = 0; u < 4; ++u) {
            vs0[u] = VGET(sp[u].x);  vd0[u] = VGET(dp[u].x);
            vs1[u] = VGET(sp[u].y);  vd1[u] = VGET(dp[u].y);
        }

        #pragma unroll
        for (int u = 0; u < 4; ++u) {
            const int pp = p + u * GSTRIDE;
            const float w0 = (1.0f / (1.0f + __expf(-lgr[u].x))) / (ppr[u].x + ppr[u].y + EPS_F);
            const float w1 = (1.0f / (1.0f + __expf(-lgr[u].y))) / (ppr[u].z + ppr[u].w + EPS_F);
            const float c0 = fabsf(vs0[u] - vd0[u]) * w0;
            const float c1 = fabsf(vs1[u] - vd1[u]) * w1;

            int4 o;
            o.x = (int)((unsigned)sp[u].x | ((unsigned)dp[u].x << 17));
            o.y = (int)((((unsigned)dp[u].x) >> 15) | ((unsigned)f2bf(c0) << 2));
            o.z = (int)((unsigned)sp[u].y | ((unsigned)dp[u].y << 17));
            o.w = (int)((((unsigned)dp[u].y) >> 15) | ((unsigned)f2bf(c1) << 2));

            if (pp < PAIRS) {
                pk[pp] = o;
                s0 += ppr[u].x + ppr[u].z;
                s1 += ppr[u].y + ppr[u].w;
                q0 += ppr[u].x * ppr[u].x + ppr[u].z * ppr[u].z;
                q1 += ppr[u].y * ppr[u].y + ppr[u].w * ppr[u].w;
            }
        }
    }
    #undef VGET

    s0 = wave_reduce(s0); s1 = wave_reduce(s1);
    q0 = wave_reduce(q0); q1 = wave_reduce(q1);

    if ((threadIdx.x & 63) == 0) {
        float4 o; o.x = s0; o.y = s1; o.z = q0; o.w = q1;
        ((float4*)(ws + VARP_OFF))[blockIdx.x * 16 + (threadIdx.x >> 6)] = o;
    }
}

// ---------------- pass 2: LDS-binned scatter — R8-proven schedule, PART store ----------------
// grid 256 (1 block/CU), 50K pairs/chunk, SBATCH=8 int4, plain float4 flush.
// Slice partners of chunk c: blockIdx = c + 32*s ≡ c (mod 8) -> same XCD;
// 4 chunks/XCD * 800 KB = 3.2 MB < 4 MB L2.
__global__ __launch_bounds__(1024) void scatter_kernel(float* __restrict__ ws)
{
    __shared__ float bins[SLICE_N];   // 50,000 B

    const int c  = blockIdx.x & (NCHUNK - 1);
    const int s  = blockIdx.x >> 5;
    const unsigned lo = (unsigned)(s * SLICE_N);

    for (int j = threadIdx.x; j < SLICE_N; j += 1024) bins[j] = 0.f;
    __syncthreads();

    const int4* pk = (const int4*)(ws + PK_OFF);

    const int p0 = c * C_PAIRS;
    const int p1 = p0 + C_PAIRS;

    for (int base = p0 + (int)threadIdx.x; base < p1; base += 1024 * SBATCH) {
        int4 q[SBATCH];
        #pragma unroll
        for (int k = 0; k < SBATCH; ++k) {
            int p = base + k * 1024;
            p = (p < p1) ? p : (p1 - 1);   // clamp: loads stay unconditional
            q[k] = pk[p];
        }
        #pragma unroll
        for (int k = 0; k < SBATCH; ++k) {
            const int p = base + k * 1024;
            if (p < p1) {
                const unsigned lo0 = (unsigned)q[k].x, hi0 = (unsigned)q[k].y;
                const unsigned lo1 = (unsigned)q[k].z, hi1 = (unsigned)q[k].w;
                const unsigned s0 = (lo0 & 0x1FFFFu) - lo;
                const unsigned d0 = ((lo0 >> 17) | ((hi0 & 3u) << 15)) - lo;
                const unsigned s1 = (lo1 & 0x1FFFFu) - lo;
                const unsigned d1 = ((lo1 >> 17) | ((hi1 & 3u) << 15)) - lo;
                const float c0 = bf2f((unsigned short)((hi0 >> 2) & 0xFFFFu));
                const float c1 = bf2f((unsigned short)((hi1 >> 2) & 0xFFFFu));
                if (d0 < SLICE_N) atomicAdd(&bins[d0],  c0);
                if (s0 < SLICE_N) atomicAdd(&bins[s0], -c0);
                if (d1 < SLICE_N) atomicAdd(&bins[d1],  c1);
                if (s1 < SLICE_N) atomicAdd(&bins[s1], -c1);
            }
        }
    }
    __syncthreads();

    float4* pt4 = (float4*)(ws + PART_OFF + (size_t)c * N_NODES + lo);
    for (int j = threadIdx.x; j < SLICE_N / 4; j += 1024)
        pt4[j] = ((const float4*)bins)[j];
}

// ---------------- pass 3: merge partials + squares; LAST block folds final ----------------
// 1024 threads x 98 blocks (was 256x391): same work, 1/4 the launch tail.
__global__ __launch_bounds__(1024) void kclfinal_kernel(float* __restrict__ ws,
                                                        float* __restrict__ out)
{
    __shared__ float red[16];
    __shared__ unsigned last;

    const int i = blockIdx.x * blockDim.x + threadIdx.x;
    float acc = 0.f;
    if (i < N_NODES) {
        const float* p = ws + PART_OFF + i;
        float s = 0.f;
        #pragma unroll 8
        for (int c = 0; c < NCHUNK; ++c) s += p[(size_t)c * N_NODES];
        acc = s * s;
    }
    acc = wave_reduce(acc);
    if ((threadIdx.x & 63) == 0) red[threadIdx.x >> 6] = acc;
    __syncthreads();
    if (threadIdx.x == 0) {
        float s = 0.f;
        #pragma unroll
        for (int w = 0; w < 16; ++w) s += red[w];
        ws[KCLP_OFF + blockIdx.x] = s;
        __threadfence();   // KCLP store visible before counter bump
        const unsigned old = atomicAdd((unsigned*)ws + CNT_WORD, 1u);
        last = (old == NKCLB - 1) ? 1u : 0u;
    }
    __syncthreads();
    if (!last) return;

    // ---- final reduction (one block, 1024 threads) ----
    __shared__ float red2[16][5];
    float s0 = 0.f, s1 = 0.f, q0 = 0.f, q1 = 0.f, k = 0.f;

    const float4* vp = (const float4*)(ws + VARP_OFF);   // prep output: kernel-boundary safe
    for (int j = threadIdx.x; j < NVARW; j += 1024) {
        const float4 v = vp[j];
        s0 += v.x; s1 += v.y; q0 += v.z; q1 += v.w;
    }
    // KCLP written by other blocks this kernel: cross-XCD L2 not coherent ->
    // read via device-scope atomic RMW (+0.0 returns old value).
    if (threadIdx.x < NKCLB)
        k = unsafeAtomicAdd(ws + KCLP_OFF + threadIdx.x, 0.0f);

    s0 = wave_reduce(s0); s1 = wave_reduce(s1);
    q0 = wave_reduce(q0); q1 = wave_reduce(q1);
    k  = wave_reduce(k);

    const int wid = threadIdx.x >> 6;
    if ((threadIdx.x & 63) == 0) {
        red2[wid][0] = s0; red2[wid][1] = s1; red2[wid][2] = q0;
        red2[wid][3] = q1; red2[wid][4] = k;
    }
    __syncthreads();
    if (threadIdx.x == 0) {
        float a0 = 0.f, a1 = 0.f, a2 = 0.f, a3 = 0.f, a4 = 0.f;
        #pragma unroll
        for (int w = 0; w < 16; ++w) {
            a0 += red2[w][0]; a1 += red2[w][1]; a2 += red2[w][2];
            a3 += red2[w][3]; a4 += red2[w][4];
        }
        const float n    = (float)N_EDGES;
        const float var0 = (a2 - a0 * a0 / n) / (n - 1.0f);
        const float var1 = (a3 - a1 * a1 / n) / (n - 1.0f);
        out[0] = a4 / (float)N_NODES + 0.5f * (var0 + var1);
    }
}

// ---------------- fallback (ws too small): agent-atomic scatter ----------------
#define FB_NODE_OFF 64
__global__ __launch_bounds__(256) void edge_kernel_fb(
    const float*  __restrict__ nf,
    const void*   __restrict__ eidx,
    const float*  __restrict__ logits,
    const float2* __restrict__ params,
    float*        __restrict__ ws)
{
    const int*       i32 = (const int*)eidx;
    const long long* i64 = (const long long*)eidx;
    int any = 0;
    #pragma unroll
    for (int k = 1; k < 32; k += 2) any |= i32[k];
    const bool is32 = (any != 0);

    float* node_sum = ws + FB_NODE_OFF;
    float* acc      = ws + 1;

    float s0 = 0.f, s1 = 0.f, q0 = 0.f, q1 = 0.f;
    const int tid    = blockIdx.x * blockDim.x + threadIdx.x;
    const int stride = gridDim.x * blockDim.x;
    for (int i = tid; i < N_EDGES; i += stride) {
        int src, dst;
        if (is32) { src = i32[i]; dst = i32[N_EDGES + i]; }
        else      { src = (int)i64[i]; dst = (int)i64[N_EDGES + i]; }
        const float2 ep = params[i];
        const float  p  = 1.0f / (1.0f + __expf(-logits[i]));
        const float cur = fabsf(nf[src * 4] - nf[dst * 4]) / (ep.x + ep.y + EPS_F) * p;
        fadd_agent(node_sum + dst,  cur);
        fadd_agent(node_sum + src, -cur);
        s0 += ep.x; s1 += ep.y; q0 += ep.x * ep.x; q1 += ep.y * ep.y;
    }
    s0 = wave_reduce(s0); s1 = wave_reduce(s1);
    q0 = wave_reduce(q0); q1 = wave_reduce(q1);
    if ((threadIdx.x & 63) == 0) {
        fadd_agent(acc + 0, s0); fadd_agent(acc + 1, s1);
        fadd_agent(acc + 2, q0); fadd_agent(acc + 3, q1);
    }
}

__global__ __launch_bounds__(256) void kcl_kernel_fb(float* __restrict__ ws)
{
    const float* node_sum = ws + FB_NODE_OFF;
    float acc = 0.f;
    const int tid    = blockIdx.x * blockDim.x + threadIdx.x;
    const int stride = gridDim.x * blockDim.x;
    for (int i = tid; i < N_NODES; i += stride) {
        const float v = node_sum[i];
        acc += v * v;
    }
    acc = wave_reduce(acc);
    if ((threadIdx.x & 63) == 0) fadd_agent(ws + 5, acc);
}

__global__ void final_kernel_fb(const float* __restrict__ ws, float* __restrict__ out)
{
    const float s0 = ws[1], s1 = ws[2], q0 = ws[3], q1 = ws[4], k = ws[5];
    const float n  = (float)N_EDGES;
    const float var0 = (q0 - s0 * s0 / n) / (n - 1.0f);
    const float var1 = (q1 - s1 * s1 / n) / (n - 1.0f);
    out[0] = k / (float)N_NODES + 0.5f * (var0 + var1);
}

extern "C" void kernel_launch(void* const* d_in, const int* in_sizes, int n_in,
                              void* d_out, int out_size, void* d_ws, size_t ws_size,
                              hipStream_t stream) {
    const float*  nf     = (const float*)d_in[0];
    const void*   eidx   = d_in[1];
    const float*  logits = (const float*)d_in[2];
    const float2* params = (const float2*)d_in[3];
    float* ws  = (float*)d_ws;
    float* out = (float*)d_out;

    const size_t need = (size_t)WS_FLOATS * sizeof(float);   // ~38.5 MB

    if (ws_size >= need) {
        prep_kernel<<<GNB, 1024, 0, stream>>>(nf, eidx, logits, params, ws);
        scatter_kernel<<<NCHUNK * NSLICE, 1024, 0, stream>>>(ws);
        kclfinal_kernel<<<NKCLB, 1024, 0, stream>>>(ws, out);
    } else {
        hipMemsetAsync(d_ws, 0, 256 + (size_t)N_NODES * sizeof(float), stream);
        edge_kernel_fb<<<2048, 256, 0, stream>>>(nf, eidx, logits, params, ws);
        kcl_kernel_fb<<<200, 256, 0, stream>>>(ws);
        final_kernel_fb<<<1, 1, 0, stream>>>(ws, out);
    }
}

// Round 12
// 166.494 us; speedup vs baseline: 1.8001x; 1.0538x over previous
//
#include <hip/hip_runtime.h>
#include <math.h>

#define N_NODES 100000
#define N_EDGES 3200000
#define EPS_F 1e-6f
#define PAIRS   (N_EDGES / 2)           // 1,600,000

// ---- prep geometry: 256 blocks x 1024 thr, 160 KB bf16 v-table in LDS ----
#define TBL_N   80000                   // bf16 nodes in LDS (160,000 B); rest spill to L2
#define GNB     256
#define GSTRIDE (GNB * 1024)            // 262,144 threads
#define NVARW   (GNB * 16)              // per-wave varsum partials (4096)

// ---- scatter: R8-proven geometry (grid 256, 50 KB bins, PART store flush) ----
// Closed by R0-R9: scatter is bound by 6.4M LDS-atomic lane-ops (~3.5 cyc each,
// 25,000/CU -> ~37 us) — invariant across scan volume, waves, iteration depth.
// R11 lesson: the 3 us pack dispatch buys a ~15 us cheaper prep (coalesced
// 160 KB table fill vs strided 1.28 MB sweep + 2B-write bank conflicts). KEEP IT.
#define SLICE_N 12500                   // 8*12500 = 100000
#define NSLICE  8
#define NCHUNK  32
#define C_PAIRS (PAIRS / NCHUNK)        // 50000 pairs per chunk (800 KB)
#define SBATCH  8

#define NKCLB   98                      // ceil(100000/1024): fewer blocks, less tail
#define NPACKB  196                     // 50176 threads >= 50000

// ws layout (4-byte words) — ~38.7 MB
//   CNT_WORD : done-counter (reset by pack_kernel)
//   PK_OFF   : u64 pack[N_EDGES]  lo = src | dst<<17 ; hi = (dst>>15) | cur<<2
//   PART_OFF : partials[NCHUNK=32][N_NODES]  (12.8 MB)
//   VARP_OFF : per-WAVE float4 {s0,s1,q0,q1}[NVARW]
//   KCLP_OFF : per-block kcl partial [NKCLB]
//   VBF_OFF  : bf16 v[N_NODES] (packed by pack_kernel; table source + spill reads)
#define CNT_WORD  32
#define PK_OFF    64
#define PART_OFF  (PK_OFF + 2 * N_EDGES)          // 6,400,064
#define VARP_OFF  (PART_OFF + NCHUNK * N_NODES)   // 9,600,064
#define KCLP_OFF  (VARP_OFF + 4 * NVARW)          // 9,616,448
#define VBF_OFF   (KCLP_OFF + 512)                // 9,616,960
#define WS_FLOATS (VBF_OFF + N_NODES / 2 + 64)

__device__ __forceinline__ float wave_reduce(float v) {
    #pragma unroll
    for (int off = 32; off > 0; off >>= 1) v += __shfl_down(v, off, 64);
    return v;
}

__device__ __forceinline__ void fadd_agent(float* p, float v) {
    unsafeAtomicAdd(p, v);   // fallback / final-reduce read path
}

// bf16 pack/unpack (RNE)
__device__ __forceinline__ unsigned short f2bf(float f) {
    unsigned u = __float_as_uint(f);
    unsigned r = ((u >> 16) & 1u) + 0x7FFFu;
    return (unsigned short)((u + r) >> 16);
}
__device__ __forceinline__ float bf2f(unsigned short h) {
    return __uint_as_float(((unsigned)h) << 16);
}

// ---------------- pass 0: pack v to bf16 (once) + reset done-counter ----------------
__global__ __launch_bounds__(256) void pack_kernel(
    const float* __restrict__ nf, float* __restrict__ ws)
{
    const int t = blockIdx.x * 256 + threadIdx.x;
    if (t == 0) ((unsigned*)ws)[CNT_WORD] = 0;
    if (t < N_NODES / 2) {
        const float4 a = ((const float4*)nf)[2 * t];       // node 2t   (v = .x)
        const float4 b = ((const float4*)nf)[2 * t + 1];   // node 2t+1 (v = .x)
        ((unsigned*)(ws + VBF_OFF))[t] = (unsigned)f2bf(a.x) | ((unsigned)f2bf(b.x) << 16);
    }
}

// ---------------- pass 1: prep = LDS v-table gather + pack ids+cur + varsum ----------------
// 80000 bf16 nodes in 160,000 B LDS (80% hit); spill ids read the bf16 global
// table (L2-resident). ILP-4: 4 independent pairs/thread.
__global__ __launch_bounds__(1024, 4) void prep_kernel(
    const void*   __restrict__ eidx,
    const float*  __restrict__ logits,
    const float2* __restrict__ params,
    float*        __restrict__ ws)
{
    __shared__ unsigned vlds[TBL_N / 2];   // 160,000 B

    // fill table (coalesced uint loads of packed bf16)
    const unsigned* vsrc = (const unsigned*)(ws + VBF_OFF);
    for (int j = threadIdx.x; j < TBL_N / 2; j += 1024) vlds[j] = vsrc[j];

    const int* i32 = (const int*)eidx;
    // int64 values < 2^31 have zero hi-words at every odd int32 slot;
    // int32 has random node ids there (16 zeros ~ impossible).
    int any = 0;
    #pragma unroll
    for (int k = 1; k < 32; k += 2) any |= i32[k];
    const bool is32 = (any != 0);

    __syncthreads();
    const unsigned short* vl = (const unsigned short*)vlds;
    const unsigned short* vg = (const unsigned short*)(ws + VBF_OFF);

    const int gtid = blockIdx.x * 1024 + threadIdx.x;
    int4* pk = (int4*)(ws + PK_OFF);

    float s0 = 0.f, s1 = 0.f, q0 = 0.f, q1 = 0.f;

    #define VGET(id) bf2f(((unsigned)(id) < TBL_N) ? vl[id] : vg[id])

    for (int p = gtid; p < PAIRS; p += 4 * GSTRIDE) {
        int pi[4];
        #pragma unroll
        for (int u = 0; u < 4; ++u) {
            const int pp = p + u * GSTRIDE;
            pi[u] = (pp < PAIRS) ? pp : p;   // clamp: loads stay unconditional
        }

        int2 sp[4], dp[4];
        if (is32) {
            #pragma unroll
            for (int u = 0; u < 4; ++u) {
                sp[u] = ((const int2*)i32)[pi[u]];
                dp[u] = ((const int2*)(i32 + N_EDGES))[pi[u]];
            }
        } else {
            #pragma unroll
            for (int u = 0; u < 4; ++u) {
                const int4 a = ((const int4*)i32)[pi[u]];
                const int4 b = ((const int4*)(i32 + 2 * N_EDGES))[pi[u]];
                sp[u] = make_int2(a.x, a.z);
                dp[u] = make_int2(b.x, b.z);
            }
        }

        float4 ppr[4];
        float2 lgr[4];
        #pragma unroll
        for (int u = 0; u < 4; ++u) {
            ppr[u] = ((const float4*)params)[pi[u]];
            lgr[u] = ((const float2*)logits)[pi[u]];
        }

        float vs0[4], vd0[4], vs1[4], vd1[4];
        #pragma unroll
        for (int u = 0; u < 4; ++u) {
            vs0[u] = VGET(sp[u].x);  vd0[u] = VGET(dp[u].x);
            vs1[u] = VGET(sp[u].y);  vd1[u] = VGET(dp[u].y);
        }

        #pragma unroll
        for (int u = 0; u < 4; ++u) {
            const int pp = p + u * GSTRIDE;
            const float w0 = (1.0f / (1.0f + __expf(-lgr[u].x))) / (ppr[u].x + ppr[u].y + EPS_F);
            const float w1 = (1.0f / (1.0f + __expf(-lgr[u].y))) / (ppr[u].z + ppr[u].w + EPS_F);
            const float c0 = fabsf(vs0[u] - vd0[u]) * w0;
            const float c1 = fabsf(vs1[u] - vd1[u]) * w1;

            int4 o;
            o.x = (int)((unsigned)sp[u].x | ((unsigned)dp[u].x << 17));
            o.y = (int)((((unsigned)dp[u].x) >> 15) | ((unsigned)f2bf(c0) << 2));
            o.z = (int)((unsigned)sp[u].y | ((unsigned)dp[u].y << 17));
            o.w = (int)((((unsigned)dp[u].y) >> 15) | ((unsigned)f2bf(c1) << 2));

            if (pp < PAIRS) {
                pk[pp] = o;
                s0 += ppr[u].x + ppr[u].z;
                s1 += ppr[u].y + ppr[u].w;
                q0 += ppr[u].x * ppr[u].x + ppr[u].z * ppr[u].z;
                q1 += ppr[u].y * ppr[u].y + ppr[u].w * ppr[u].w;
            }
        }
    }
    #undef VGET

    s0 = wave_reduce(s0); s1 = wave_reduce(s1);
    q0 = wave_reduce(q0); q1 = wave_reduce(q1);

    if ((threadIdx.x & 63) == 0) {
        float4 o; o.x = s0; o.y = s1; o.z = q0; o.w = q1;
        ((float4*)(ws + VARP_OFF))[blockIdx.x * 16 + (threadIdx.x >> 6)] = o;
    }
}

// ---------------- pass 2: LDS-binned scatter — R8-proven schedule, PART store ----------------
// grid 256 (1 block/CU), 50K pairs/chunk, SBATCH=8 int4, plain float4 flush.
// Slice partners of chunk c: blockIdx = c + 32*s ≡ c (mod 8) -> same XCD;
// 4 chunks/XCD * 800 KB = 3.2 MB < 4 MB L2.
__global__ __launch_bounds__(1024) void scatter_kernel(float* __restrict__ ws)
{
    __shared__ float bins[SLICE_N];   // 50,000 B

    const int c  = blockIdx.x & (NCHUNK - 1);
    const int s  = blockIdx.x >> 5;
    const unsigned lo = (unsigned)(s * SLICE_N);

    for (int j = threadIdx.x; j < SLICE_N; j += 1024) bins[j] = 0.f;
    __syncthreads();

    const int4* pk = (const int4*)(ws + PK_OFF);

    const int p0 = c * C_PAIRS;
    const int p1 = p0 + C_PAIRS;

    for (int base = p0 + (int)threadIdx.x; base < p1; base += 1024 * SBATCH) {
        int4 q[SBATCH];
        #pragma unroll
        for (int k = 0; k < SBATCH; ++k) {
            int p = base + k * 1024;
            p = (p < p1) ? p : (p1 - 1);   // clamp: loads stay unconditional
            q[k] = pk[p];
        }
        #pragma unroll
        for (int k = 0; k < SBATCH; ++k) {
            const int p = base + k * 1024;
            if (p < p1) {
                const unsigned lo0 = (unsigned)q[k].x, hi0 = (unsigned)q[k].y;
                const unsigned lo1 = (unsigned)q[k].z, hi1 = (unsigned)q[k].w;
                const unsigned s0 = (lo0 & 0x1FFFFu) - lo;
                const unsigned d0 = ((lo0 >> 17) | ((hi0 & 3u) << 15)) - lo;
                const unsigned s1 = (lo1 & 0x1FFFFu) - lo;
                const unsigned d1 = ((lo1 >> 17) | ((hi1 & 3u) << 15)) - lo;
                const float c0 = bf2f((unsigned short)((hi0 >> 2) & 0xFFFFu));
                const float c1 = bf2f((unsigned short)((hi1 >> 2) & 0xFFFFu));
                if (d0 < SLICE_N) atomicAdd(&bins[d0],  c0);
                if (s0 < SLICE_N) atomicAdd(&bins[s0], -c0);
                if (d1 < SLICE_N) atomicAdd(&bins[d1],  c1);
                if (s1 < SLICE_N) atomicAdd(&bins[s1], -c1);
            }
        }
    }
    __syncthreads();

    float4* pt4 = (float4*)(ws + PART_OFF + (size_t)c * N_NODES + lo);
    for (int j = threadIdx.x; j < SLICE_N / 4; j += 1024)
        pt4[j] = ((const float4*)bins)[j];
}

// ---------------- pass 3: merge partials + squares; LAST block folds final ----------------
// 1024 threads x 98 blocks: same work as 256x391, 1/4 the launch tail.
__global__ __launch_bounds__(1024) void kclfinal_kernel(float* __restrict__ ws,
                                                        float* __restrict__ out)
{
    __shared__ float red[16];
    __shared__ unsigned last;

    const int i = blockIdx.x * blockDim.x + threadIdx.x;
    float acc = 0.f;
    if (i < N_NODES) {
        const float* p = ws + PART_OFF + i;
        float s = 0.f;
        #pragma unroll 8
        for (int c = 0; c < NCHUNK; ++c) s += p[(size_t)c * N_NODES];
        acc = s * s;
    }
    acc = wave_reduce(acc);
    if ((threadIdx.x & 63) == 0) red[threadIdx.x >> 6] = acc;
    __syncthreads();
    if (threadIdx.x == 0) {
        float s = 0.f;
        #pragma unroll
        for (int w = 0; w < 16; ++w) s += red[w];
        ws[KCLP_OFF + blockIdx.x] = s;
        __threadfence();   // KCLP store visible before counter bump
        const unsigned old = atomicAdd((unsigned*)ws + CNT_WORD, 1u);
        last = (old == NKCLB - 1) ? 1u : 0u;
    }
    __syncthreads();
    if (!last) return;

    // ---- final reduction (one block, 1024 threads) ----
    __shared__ float red2[16][5];
    float s0 = 0.f, s1 = 0.f, q0 = 0.f, q1 = 0.f, k = 0.f;

    const float4* vp = (const float4*)(ws + VARP_OFF);   // prep output: kernel-boundary safe
    for (int j = threadIdx.x; j < NVARW; j += 1024) {
        const float4 v = vp[j];
        s0 += v.x; s1 += v.y; q0 += v.z; q1 += v.w;
    }
    // KCLP written by other blocks this kernel: cross-XCD L2 not coherent ->
    // read via device-scope atomic RMW (+0.0 returns old value).
    if (threadIdx.x < NKCLB)
        k = unsafeAtomicAdd(ws + KCLP_OFF + threadIdx.x, 0.0f);

    s0 = wave_reduce(s0); s1 = wave_reduce(s1);
    q0 = wave_reduce(q0); q1 = wave_reduce(q1);
    k  = wave_reduce(k);

    const int wid = threadIdx.x >> 6;
    if ((threadIdx.x & 63) == 0) {
        red2[wid][0] = s0; red2[wid][1] = s1; red2[wid][2] = q0;
        red2[wid][3] = q1; red2[wid][4] = k;
    }
    __syncthreads();
    if (threadIdx.x == 0) {
        float a0 = 0.f, a1 = 0.f, a2 = 0.f, a3 = 0.f, a4 = 0.f;
        #pragma unroll
        for (int w = 0; w < 16; ++w) {
            a0 += red2[w][0]; a1 += red2[w][1]; a2 += red2[w][2];
            a3 += red2[w][3]; a4 += red2[w][4];
        }
        const float n    = (float)N_EDGES;
        const float var0 = (a2 - a0 * a0 / n) / (n - 1.0f);
        const float var1 = (a3 - a1 * a1 / n) / (n - 1.0f);
        out[0] = a4 / (float)N_NODES + 0.5f * (var0 + var1);
    }
}

// ---------------- fallback (ws too small): agent-atomic scatter ----------------
#define FB_NODE_OFF 64
__global__ __launch_bounds__(256) void edge_kernel_fb(
    const float*  __restrict__ nf,
    const void*   __restrict__ eidx,
    const float*  __restrict__ logits,
    const float2* __restrict__ params,
    float*        __restrict__ ws)
{
    const int*       i32 = (const int*)eidx;
    const long long* i64 = (const long long*)eidx;
    int any = 0;
    #pragma unroll
    for (int k = 1; k < 32; k += 2) any |= i32[k];
    const bool is32 = (any != 0);

    float* node_sum = ws + FB_NODE_OFF;
    float* acc      = ws + 1;

    float s0 = 0.f, s1 = 0.f, q0 = 0.f, q1 = 0.f;
    const int tid    = blockIdx.x * blockDim.x + threadIdx.x;
    const int stride = gridDim.x * blockDim.x;
    for (int i = tid; i < N_EDGES; i += stride) {
        int src, dst;
        if (is32) { src = i32[i]; dst = i32[N_EDGES + i]; }
        else      { src = (int)i64[i]; dst = (int)i64[N_EDGES + i]; }
        const float2 ep = params[i];
        const float  p  = 1.0f / (1.0f + __expf(-logits[i]));
        const float cur = fabsf(nf[src * 4] - nf[dst * 4]) / (ep.x + ep.y + EPS_F) * p;
        fadd_agent(node_sum + dst,  cur);
        fadd_agent(node_sum + src, -cur);
        s0 += ep.x; s1 += ep.y; q0 += ep.x * ep.x; q1 += ep.y * ep.y;
    }
    s0 = wave_reduce(s0); s1 = wave_reduce(s1);
    q0 = wave_reduce(q0); q1 = wave_reduce(q1);
    if ((threadIdx.x & 63) == 0) {
        fadd_agent(acc + 0, s0); fadd_agent(acc + 1, s1);
        fadd_agent(acc + 2, q0); fadd_agent(acc + 3, q1);
    }
}

__global__ __launch_bounds__(256) void kcl_kernel_fb(float* __restrict__ ws)
{
    const float* node_sum = ws + FB_NODE_OFF;
    float acc = 0.f;
    const int tid    = blockIdx.x * blockDim.x + threadIdx.x;
    const int stride = gridDim.x * blockDim.x;
    for (int i = tid; i < N_NODES; i += stride) {
        const float v = node_sum[i];
        acc += v * v;
    }
    acc = wave_reduce(acc);
    if ((threadIdx.x & 63) == 0) fadd_agent(ws + 5, acc);
}

__global__ void final_kernel_fb(const float* __restrict__ ws, float* __restrict__ out)
{
    const float s0 = ws[1], s1 = ws[2], q0 = ws[3], q1 = ws[4], k = ws[5];
    const float n  = (float)N_EDGES;
    const float var0 = (q0 - s0 * s0 / n) / (n - 1.0f);
    const float var1 = (q1 - s1 * s1 / n) / (n - 1.0f);
    out[0] = k / (float)N_NODES + 0.5f * (var0 + var1);
}

extern "C" void kernel_launch(void* const* d_in, const int* in_sizes, int n_in,
                              void* d_out, int out_size, void* d_ws, size_t ws_size,
                              hipStream_t stream) {
    const float*  nf     = (const float*)d_in[0];
    const void*   eidx   = d_in[1];
    const float*  logits = (const float*)d_in[2];
    const float2* params = (const float2*)d_in[3];
    float* ws  = (float*)d_ws;
    float* out = (float*)d_out;

    const size_t need = (size_t)WS_FLOATS * sizeof(float);   // ~38.7 MB

    if (ws_size >= need) {
        pack_kernel<<<NPACKB, 256, 0, stream>>>(nf, ws);
        prep_kernel<<<GNB, 1024, 0, stream>>>(eidx, logits, params, ws);
        scatter_kernel<<<NCHUNK * NSLICE, 1024, 0, stream>>>(ws);
        kclfinal_kernel<<<NKCLB, 1024, 0, stream>>>(ws, out);
    } else {
        hipMemsetAsync(d_ws, 0, 256 + (size_t)N_NODES * sizeof(float), stream);
        edge_kernel_fb<<<2048, 256, 0, stream>>>(nf, eidx, logits, params, ws);
        kcl_kernel_fb<<<200, 256, 0, stream>>>(ws);
        final_kernel_fb<<<1, 1, 0, stream>>>(ws, out);
    }
}